// Round 9
// baseline (445.717 us; speedup 1.0000x reference)
//
#include <hip/hip_runtime.h>

#define T_ 8
#define N_ 50000
#define E_ 800000
#define C_ 64

typedef __attribute__((ext_vector_type(8))) short bf16x8;
typedef __attribute__((ext_vector_type(4))) float f32x4;

__device__ inline short f2bf(float f) {
    union { float f; unsigned int u; } v; v.f = f;
    unsigned int u = v.u + 0x7FFFu + ((v.u >> 16) & 1u);  // RNE
    return (short)(u >> 16);
}
__device__ inline float bf2f_lo(unsigned int u) {
    union { unsigned int u; float f; } v; v.u = u << 16;
    return v.f;
}
__device__ inline float bf2f_hi(unsigned int u) {
    union { unsigned int u; float f; } v; v.u = u & 0xffff0000u;
    return v.f;
}

#define SCAN_TILES 49  // ceil(N / 1024)

// ---------------------------------------------------------------------------
// 1) fused: hist (blocks [0,3125)) + xcvt (blocks [3125,15625)) + wprep (rest)
__global__ __launch_bounds__(256) void fused_prep_kernel(
        const int* __restrict__ src, const int* __restrict__ dst,
        const float* __restrict__ w,
        float* __restrict__ degw, int* __restrict__ cnt,
        const float* __restrict__ x, unsigned short* __restrict__ xb,
        const float* __restrict__ Wz0, const float* __restrict__ Wz1,
        const float* __restrict__ Wh0, const float* __restrict__ Wh1,
        short* __restrict__ swz) {
    if (blockIdx.x < 3125) {
        int e = blockIdx.x * 256 + threadIdx.x;
        if (e < E_) {
            atomicAdd(&degw[src[e]], w[e]);
            atomicAdd(&cnt[dst[e]], 1);
        }
    } else if (blockIdx.x < 15625) {
        long long i = ((long long)(blockIdx.x - 3125) * 256 + threadIdx.x) * 8;
        float4 a = *(const float4*)(x + i);
        float4 b = *(const float4*)(x + i + 4);
        bf16x8 o;
        o[0] = f2bf(a.x); o[1] = f2bf(a.y); o[2] = f2bf(a.z); o[3] = f2bf(a.w);
        o[4] = f2bf(b.x); o[5] = f2bf(b.y); o[6] = f2bf(b.z); o[7] = f2bf(b.w);
        *(bf16x8*)(xb + i) = o;
    } else {
        int idx = (blockIdx.x - 15625) * 256 + threadIdx.x;  // < 16384
        int j = idx & 7;
        int lane = (idx >> 3) & 63;
        int kb = (idx >> 9) & 1;
        int c = (idx >> 10) & 3;
        int mat = idx >> 12;
        const float* W = (mat == 0) ? Wz0 : (mat == 1) ? Wz1 : (mat == 2) ? Wh0 : Wh1;
        int k = kb * 32 + (lane >> 4) * 8 + j;
        int n = c * 16 + (lane & 15);
        swz[idx] = f2bf(W[k * 64 + n]);
    }
}

// 2a) parallel scan pass A: per-tile exclusive scan + tile totals
__global__ __launch_bounds__(1024) void scan_a_kernel(const int* __restrict__ cnt,
                                                      int* __restrict__ rowptr,
                                                      int* __restrict__ tsum) {
    __shared__ int wsum[16];
    int tid = threadIdx.x, lane = tid & 63, wid = tid >> 6;
    int idx = blockIdx.x * 1024 + tid;
    int orig = (idx < N_) ? cnt[idx] : 0;
    int v = orig;
#pragma unroll
    for (int off = 1; off < 64; off <<= 1) {
        int u = __shfl_up(v, off);
        if (lane >= off) v += u;
    }
    if (lane == 63) wsum[wid] = v;
    __syncthreads();
    if (wid == 0) {
        int s = (lane < 16) ? wsum[lane] : 0;
#pragma unroll
        for (int off = 1; off < 16; off <<= 1) {
            int u = __shfl_up(s, off);
            if (lane >= off) s += u;
        }
        if (lane < 16) wsum[lane] = s;
    }
    __syncthreads();
    int wpre = wid ? wsum[wid - 1] : 0;
    if (idx < N_) rowptr[idx] = wpre + v - orig;
    if (tid == 0) tsum[blockIdx.x] = wsum[15];
}

// 2b) pass B: every block redundantly scans the 49 tile totals, adds its offset
__global__ __launch_bounds__(1024) void scan_b_kernel(const int* __restrict__ tsum,
                                                      int* __restrict__ rowptr) {
    __shared__ int soff[SCAN_TILES];
    __shared__ int stot;
    int tid = threadIdx.x, lane = tid & 63, wid = tid >> 6;
    if (wid == 0) {
        int own = (lane < SCAN_TILES) ? tsum[lane] : 0;
        int s = own;
#pragma unroll
        for (int off = 1; off < 64; off <<= 1) {
            int u = __shfl_up(s, off);
            if (lane >= off) s += u;
        }
        if (lane < SCAN_TILES) soff[lane] = s - own;  // exclusive
        if (lane == SCAN_TILES - 1) stot = s;
    }
    __syncthreads();
    int off = soff[blockIdx.x];
    int idx = blockIdx.x * 1024 + tid;
    if (idx < N_) rowptr[idx] += off;
    if (blockIdx.x == SCAN_TILES - 1 && tid == 0) rowptr[N_] = stot;
}

// 3) reorder edges into CSR-by-dst, dinv fused. Afterwards rowptr[d]==end(d),
//    start(d)==(d?rowptr[d-1]:0). Packs {src,nw}.
__global__ void reorder_kernel(const int* __restrict__ src, const int* __restrict__ dst,
                               const float* __restrict__ w, const float* __restrict__ degw,
                               int* __restrict__ rowptr, int2* __restrict__ es, int E) {
    int e = blockIdx.x * blockDim.x + threadIdx.x;
    if (e < E) {
        int s = src[e], d = dst[e];
        float ds = degw[s], dd = degw[d];
        float is = ds > 0.f ? rsqrtf(fmaxf(ds, 1e-12f)) : 0.f;
        float id = dd > 0.f ? rsqrtf(fmaxf(dd, 1e-12f)) : 0.f;
        float nwv = -w[e] * is * id;
        int pos = atomicAdd(&rowptr[d], 1);
        es[pos] = make_int2(s, __float_as_int(nwv));
    }
}

// 4) WAVE-AUTONOMOUS fused gather + MFMA + epilogue. No __syncthreads.
//    Each wave owns 2 adjacent nodes (16 block-rows = one M-tile):
//      phase 1: gather tx1 for d0 then d1 (lane = t*8+oct), park in private LDS
//      phase 2: MFMA both gates (az, ah) from xb + LDS A-frags, swz B-frags
//      phase 3: in-lane epilogue (az/ah same lane), Wlin shfl-reduce, store.
__global__ __launch_bounds__(256) void gather_node_kernel(
        const int* __restrict__ rowptr, const int2* __restrict__ es,
        const unsigned short* __restrict__ xb, const short* __restrict__ swz,
        const float* __restrict__ bxz, const float* __restrict__ bhz,
        const float* __restrict__ bxh, const float* __restrict__ bhh,
        const float* __restrict__ Wlin, const float* __restrict__ blin,
        float* __restrict__ out) {
    __shared__ unsigned short ltx[4][16 * 72];  // per-wave 16 rows x 64ch bf16 (+8 pad)

    int lane = threadIdx.x & 63;
    int wid = threadIdx.x >> 6;
    int d0 = (blockIdx.x * 4 + wid) * 2;
    unsigned short* ltx_w = &ltx[wid][0];

    // ---- phase 1: gather both nodes (lane = t*8 + oct) ----
    int t = lane >> 3;
    int oct = lane & 7;
    const unsigned short* xbase = xb + (long long)t * N_ * C_ + oct * 8;
#pragma unroll
    for (int nn = 0; nn < 2; ++nn) {
        int d = d0 + nn;
        int start = d ? rowptr[d - 1] : 0;
        int end = rowptr[d];
        float acc[8] = {0.f, 0.f, 0.f, 0.f, 0.f, 0.f, 0.f, 0.f};
        for (int b0 = start; b0 < end; b0 += 64) {
            int m = end - b0;
            if (m > 64) m = 64;
            int2 pk = (lane < m) ? es[b0 + lane] : make_int2(0, 0);
            int k = 0;
            for (; k + 1 < m; k += 2) {
                int s0 = __shfl(pk.x, k);
                float w0 = __int_as_float(__shfl(pk.y, k));
                int s1 = __shfl(pk.x, k + 1);
                float w1 = __int_as_float(__shfl(pk.y, k + 1));
                uint4 v0 = *(const uint4*)(xbase + (long long)s0 * C_);
                uint4 v1 = *(const uint4*)(xbase + (long long)s1 * C_);
                acc[0] += w0 * bf2f_lo(v0.x); acc[1] += w0 * bf2f_hi(v0.x);
                acc[2] += w0 * bf2f_lo(v0.y); acc[3] += w0 * bf2f_hi(v0.y);
                acc[4] += w0 * bf2f_lo(v0.z); acc[5] += w0 * bf2f_hi(v0.z);
                acc[6] += w0 * bf2f_lo(v0.w); acc[7] += w0 * bf2f_hi(v0.w);
                acc[0] += w1 * bf2f_lo(v1.x); acc[1] += w1 * bf2f_hi(v1.x);
                acc[2] += w1 * bf2f_lo(v1.y); acc[3] += w1 * bf2f_hi(v1.y);
                acc[4] += w1 * bf2f_lo(v1.z); acc[5] += w1 * bf2f_hi(v1.z);
                acc[6] += w1 * bf2f_lo(v1.w); acc[7] += w1 * bf2f_hi(v1.w);
            }
            if (k < m) {
                int s0 = __shfl(pk.x, k);
                float w0 = __int_as_float(__shfl(pk.y, k));
                uint4 v0 = *(const uint4*)(xbase + (long long)s0 * C_);
                acc[0] += w0 * bf2f_lo(v0.x); acc[1] += w0 * bf2f_hi(v0.x);
                acc[2] += w0 * bf2f_lo(v0.y); acc[3] += w0 * bf2f_hi(v0.y);
                acc[4] += w0 * bf2f_lo(v0.z); acc[5] += w0 * bf2f_hi(v0.z);
                acc[6] += w0 * bf2f_lo(v0.w); acc[7] += w0 * bf2f_hi(v0.w);
            }
        }
        uint4 o;
        o.x = (unsigned int)(unsigned short)f2bf(acc[0]) |
              ((unsigned int)(unsigned short)f2bf(acc[1]) << 16);
        o.y = (unsigned int)(unsigned short)f2bf(acc[2]) |
              ((unsigned int)(unsigned short)f2bf(acc[3]) << 16);
        o.z = (unsigned int)(unsigned short)f2bf(acc[4]) |
              ((unsigned int)(unsigned short)f2bf(acc[5]) << 16);
        o.w = (unsigned int)(unsigned short)f2bf(acc[6]) |
              ((unsigned int)(unsigned short)f2bf(acc[7]) << 16);
        int r = nn * 8 + t;
        *(uint4*)(ltx_w + r * 72 + oct * 8) = o;
    }
    // no barrier: wave-local LDS round-trip, compiler inserts lgkmcnt waits

    // ---- phase 2: MFMA both gates for this wave's 16 rows ----
    int c16 = lane & 15;   // block-row: node d0+(c16>>3), t = c16&7
    int kq = lane >> 4;
    int tt = c16 & 7;
    int dd = d0 + (c16 >> 3);

    const unsigned short* xr = xb + ((long long)tt * N_ + dd) * C_ + kq * 8;
    bf16x8 ax0 = *(const bf16x8*)(xr);
    bf16x8 ax1 = *(const bf16x8*)(xr + 32);
    bf16x8 at0 = *(const bf16x8*)(ltx_w + c16 * 72 + kq * 8);
    bf16x8 at1 = *(const bf16x8*)(ltx_w + c16 * 72 + 32 + kq * 8);

    f32x4 az[4], ah[4];
#pragma unroll
    for (int c = 0; c < 4; ++c) {
        int col = c * 16 + c16;
        float bz = bxz[col] + bhz[col];
        float bh = bxh[col] + bhh[col];
        az[c] = (f32x4){bz, bz, bz, bz};
        ah[c] = (f32x4){bh, bh, bh, bh};
    }
    const short* wz0 = swz + 0 * 4096 + lane * 8;
    const short* wz1 = swz + 1 * 4096 + lane * 8;
    const short* wh0 = swz + 2 * 4096 + lane * 8;
    const short* wh1 = swz + 3 * 4096 + lane * 8;
#pragma unroll
    for (int c = 0; c < 4; ++c) {
        bf16x8 bz0 = *(const bf16x8*)(wz0 + (c * 2 + 0) * 512);
        bf16x8 bz1 = *(const bf16x8*)(wz0 + (c * 2 + 1) * 512);
        bf16x8 bt0 = *(const bf16x8*)(wz1 + (c * 2 + 0) * 512);
        bf16x8 bt1 = *(const bf16x8*)(wz1 + (c * 2 + 1) * 512);
        az[c] = __builtin_amdgcn_mfma_f32_16x16x32_bf16(ax0, bz0, az[c], 0, 0, 0);
        az[c] = __builtin_amdgcn_mfma_f32_16x16x32_bf16(ax1, bz1, az[c], 0, 0, 0);
        az[c] = __builtin_amdgcn_mfma_f32_16x16x32_bf16(at0, bt0, az[c], 0, 0, 0);
        az[c] = __builtin_amdgcn_mfma_f32_16x16x32_bf16(at1, bt1, az[c], 0, 0, 0);
        bf16x8 bh0 = *(const bf16x8*)(wh0 + (c * 2 + 0) * 512);
        bf16x8 bh1 = *(const bf16x8*)(wh0 + (c * 2 + 1) * 512);
        bf16x8 bu0 = *(const bf16x8*)(wh1 + (c * 2 + 0) * 512);
        bf16x8 bu1 = *(const bf16x8*)(wh1 + (c * 2 + 1) * 512);
        ah[c] = __builtin_amdgcn_mfma_f32_16x16x32_bf16(ax0, bh0, ah[c], 0, 0, 0);
        ah[c] = __builtin_amdgcn_mfma_f32_16x16x32_bf16(ax1, bh1, ah[c], 0, 0, 0);
        ah[c] = __builtin_amdgcn_mfma_f32_16x16x32_bf16(at0, bu0, ah[c], 0, 0, 0);
        ah[c] = __builtin_amdgcn_mfma_f32_16x16x32_bf16(at1, bu1, ah[c], 0, 0, 0);
    }

    // ---- phase 3: epilogue, all in-lane (az/ah share (row,col) mapping) ----
    float part[4] = {0.f, 0.f, 0.f, 0.f};
#pragma unroll
    for (int c = 0; c < 4; ++c) {
        int col = c * 16 + c16;
        float wl = Wlin[col];
#pragma unroll
        for (int r = 0; r < 4; ++r) {
            float a = az[c][r];
            float b = ah[c][r];
            float z = 1.f / (1.f + __expf(-a));
            float aa = fabsf(b);
            float e = __expf(-2.f * aa);
            float ht = copysignf((1.f - e) / (1.f + e), b);
            float h = fmaxf((1.f - z) * ht, 0.f);
            part[r] += h * wl;
        }
    }
#pragma unroll
    for (int m = 1; m <= 8; m <<= 1) {
#pragma unroll
        for (int r = 0; r < 4; ++r) part[r] += __shfl_xor(part[r], m);
    }
    if (c16 == 0) {
        float bl = blin[0];
#pragma unroll
        for (int r = 0; r < 4; ++r) {
            int rb = kq * 4 + r;  // 0..15: node d0+(rb>>3), t = rb&7
            out[(long long)(rb & 7) * N_ + d0 + (rb >> 3)] = part[r] + bl;
        }
    }
}

extern "C" void kernel_launch(void* const* d_in, const int* in_sizes, int n_in,
                              void* d_out, int out_size, void* d_ws, size_t ws_size,
                              hipStream_t stream) {
    const float* x    = (const float*)d_in[0];
    const int*   ei   = (const int*)d_in[1];
    const float* w    = (const float*)d_in[2];
    const float* Wxz0 = (const float*)d_in[3];
    const float* Wxz1 = (const float*)d_in[4];
    const float* bxz  = (const float*)d_in[5];
    const float* bhz  = (const float*)d_in[8];
    const float* Wxh0 = (const float*)d_in[15];
    const float* Wxh1 = (const float*)d_in[16];
    const float* bxh  = (const float*)d_in[17];
    const float* bhh  = (const float*)d_in[20];
    const float* Wlin = (const float*)d_in[21];
    const float* blin = (const float*)d_in[22];
    float* out = (float*)d_out;

    const int* src = ei;
    const int* dst = ei + E_;

    // workspace layout (512-aligned blocks):
    char* ws = (char*)d_ws;
    size_t off = 0;
    auto alloc = [&](size_t bytes) {
        char* p = ws + off;
        off = (off + bytes + 511) & ~(size_t)511;
        return p;
    };
    short* swz             = (short*)alloc(4 * 4096 * sizeof(short));           // 32 KB
    float* degw            = (float*)alloc((size_t)N_ * 4);
    int*   cnt             = (int*)alloc((size_t)N_ * 4);   // adjacent to degw
    int*   rowptr          = (int*)alloc(((size_t)N_ + 1) * 4);
    int*   tsum            = (int*)alloc((size_t)SCAN_TILES * 4);
    int2*  es              = (int2*)alloc((size_t)E_ * 8);                      // 6.4 MB
    unsigned short* xb     = (unsigned short*)alloc((size_t)T_ * N_ * C_ * 2);  // 51.2 MB

    // one memset covers degw (padded) + cnt
    hipMemsetAsync(degw, 0, (size_t)((char*)cnt - (char*)degw) + (size_t)N_ * 4, stream);

    // hist (3125) + xcvt (12500) + wprep (64) = 15689 blocks
    fused_prep_kernel<<<15689, 256, 0, stream>>>(src, dst, w, degw, cnt,
                                                 x, xb, Wxz0, Wxz1, Wxh0, Wxh1, swz);
    scan_a_kernel<<<SCAN_TILES, 1024, 0, stream>>>(cnt, rowptr, tsum);
    scan_b_kernel<<<SCAN_TILES, 1024, 0, stream>>>(tsum, rowptr);
    reorder_kernel<<<(E_ + 255) / 256, 256, 0, stream>>>(src, dst, w, degw, rowptr, es, E_);

    // 6250 blocks x 4 waves x 2 nodes = 50000
    gather_node_kernel<<<N_ / 8, 256, 0, stream>>>(
        rowptr, es, xb, swz, bxz, bhz, bxh, bhh, Wlin, blin, out);
}